// Round 1
// baseline (498.749 us; speedup 1.0000x reference)
//
#include <hip/hip_runtime.h>

// ExpansionContrastModule on MI355X (gfx950), bf16 MFMA pipeline.
// All GEMMs are TN form: D[M][N] = X[M][K] · Y[N][K]^T via mfma_f32_16x16x32_bf16.
// Reductions (L2 norm, instance-norm, softmax, BN) stay in f32.

typedef unsigned short u16;
typedef unsigned int u32;
typedef __attribute__((ext_vector_type(4))) unsigned int u32x4;
typedef __attribute__((ext_vector_type(8))) short s16x8;
typedef __attribute__((ext_vector_type(4))) float f32x4;

#define DEVFN static __device__ __forceinline__

DEVFN u16 f2bf(float f) {
    u32 u = __builtin_bit_cast(u32, f);
    u32 r = (u + 0x7fffu + ((u >> 16) & 1u)) >> 16;  // RNE
    return (u16)r;
}
DEVFN float bf2f(u32 h) { u32 u = h << 16; return __builtin_bit_cast(float, u); }

// OFFSETS = [(-1,-1),(-1,0),(-1,1),(0,1),(1,1),(1,0),(1,-1),(0,-1)]
__constant__ int cOFFY[8] = {-1,-1,-1, 0, 1, 1, 1, 0};
__constant__ int cOFFX[8] = {-1, 0, 1, 1, 1, 0,-1,-1};

// XOR swizzle within a 128B LDS row (BK=64 bf16): spreads same-k columns of
// 8 consecutive rows over 8 distinct 16B slots -> b128 reads/writes at the
// 8-pass floor (no extra bank conflicts).
DEVFN int swz(int r, int kb) { return r * 128 + (kb ^ ((r & 7) << 4)); }

// ---------------------------------------------------------------------------
// Generic TN GEMM. BK=64 fixed. 256 threads = 4 waves in a 2x2 grid.
// XG/YG: operand is gathered from cen_t with dilated shifts (rows = area idx).
// DM: 0 = bf16 out, 1 = f32 out, 2 = locs scatter into VLt (bf16).
// batch z: b = z>>sbits, s = z & mask.
// ---------------------------------------------------------------------------
template<int BM, int BN, int WRM, int WRN, int XG, int YG, int DM>
__global__ __launch_bounds__(256, 2)
void gemm_tn(const u16* __restrict__ X, const u16* __restrict__ Y,
             void* __restrict__ D, const u16* __restrict__ cenT,
             int K, int ldx, int ldy, int ldd, int sbits,
             long xb, long xs, long yb, long ys, long db, long dsn)
{
    constexpr int NCX = BM * 8 / 256;   // 16B chunks per thread, X tile
    constexpr int NCY = BN * 8 / 256;
    const int tid  = threadIdx.x;
    const int lane = tid & 63;
    const int wid  = tid >> 6;
    const int z = blockIdx.z;
    const int b = z >> sbits;
    const int s = z & ((1 << sbits) - 1);
    const int m0 = blockIdx.x * BM;
    const int n0 = blockIdx.y * BN;
    const int dil = s + 1;
    const int wm0 = (wid >> 1) * (WRM * 16);
    const int wn0 = (wid & 1) * (WRN * 16);

    __shared__ __align__(16) char lds[2 * (BM + BN) * 128];

    const u16* cenB = cenT + (long)b * (4096 * 256);
    const u16* Xt = nullptr;
    const u16* Yt = nullptr;
    if constexpr (!XG)
        Xt = X + b * xb + (long)s * xs + (long)m0 * ldx + (long)(tid >> 3) * ldx + (tid & 7) * 8;
    if constexpr (!YG)
        Yt = Y + b * yb + (long)s * ys + (long)n0 * ldy + (long)(tid >> 3) * ldy + (tid & 7) * 8;

    int gyX[XG ? NCX : 1], gxX[XG ? NCX : 1];
    int gyY[YG ? NCY : 1], gxY[YG ? NCY : 1];
    if constexpr (XG) {
        #pragma unroll
        for (int c = 0; c < NCX; c++) { int a = m0 + c * 32 + (tid >> 3); gyX[c] = a >> 6; gxX[c] = a & 63; }
    }
    if constexpr (YG) {
        #pragma unroll
        for (int c = 0; c < NCY; c++) { int a = n0 + c * 32 + (tid >> 3); gyY[c] = a >> 6; gxY[c] = a & 63; }
    }

    f32x4 acc[WRM][WRN] = {};
    u32x4 xv[NCX], yv[NCY];

    auto loadX = [&](int t) {
        if constexpr (!XG) {
            #pragma unroll
            for (int c = 0; c < NCX; c++)
                xv[c] = *(const u32x4*)(Xt + (long)c * 32 * ldx + t * 64);
        } else {
            const int j = t >> 2;                 // BK=64, 256 chans per offset block
            const int dy = cOFFY[j] * dil, dx = cOFFX[j] * dil;
            const int cb = (t * 64) & 255;
            #pragma unroll
            for (int c = 0; c < NCX; c++) {
                int yy = gyX[c] + dy, xx = gxX[c] + dx;
                u32x4 v = {0, 0, 0, 0};
                if (((unsigned)yy < 64u) && ((unsigned)xx < 64u))
                    v = *(const u32x4*)(cenB + (((yy << 6) + xx) << 8) + cb + (tid & 7) * 8);
                xv[c] = v;
            }
        }
    };
    auto loadY = [&](int t) {
        if constexpr (!YG) {
            #pragma unroll
            for (int c = 0; c < NCY; c++)
                yv[c] = *(const u32x4*)(Yt + (long)c * 32 * ldy + t * 64);
        } else {
            const int j = t >> 2;
            const int dy = cOFFY[j] * dil, dx = cOFFX[j] * dil;
            const int cb = (t * 64) & 255;
            #pragma unroll
            for (int c = 0; c < NCY; c++) {
                int yy = gyY[c] + dy, xx = gxY[c] + dx;
                u32x4 v = {0, 0, 0, 0};
                if (((unsigned)yy < 64u) && ((unsigned)xx < 64u))
                    v = *(const u32x4*)(cenB + (((yy << 6) + xx) << 8) + cb + (tid & 7) * 8);
                yv[c] = v;
            }
        }
    };
    auto writeT = [&](int buf) {
        char* LX = lds + buf * ((BM + BN) * 128);
        char* LY = LX + BM * 128;
        #pragma unroll
        for (int c = 0; c < NCX; c++)
            *(u32x4*)(LX + swz(c * 32 + (tid >> 3), (tid & 7) * 16)) = xv[c];
        #pragma unroll
        for (int c = 0; c < NCY; c++)
            *(u32x4*)(LY + swz(c * 32 + (tid >> 3), (tid & 7) * 16)) = yv[c];
    };
    auto comp = [&](int buf) {
        const char* LX = lds + buf * ((BM + BN) * 128);
        const char* LY = LX + BM * 128;
        #pragma unroll
        for (int kk = 0; kk < 2; kk++) {
            const int kb = kk * 64 + ((lane >> 4) << 4);
            s16x8 af[WRM], bfr[WRN];
            #pragma unroll
            for (int m = 0; m < WRM; m++)
                af[m] = *(const s16x8*)(LX + swz(wm0 + m * 16 + (lane & 15), kb));
            #pragma unroll
            for (int n = 0; n < WRN; n++)
                bfr[n] = *(const s16x8*)(LY + swz(wn0 + n * 16 + (lane & 15), kb));
            #pragma unroll
            for (int m = 0; m < WRM; m++)
                #pragma unroll
                for (int n = 0; n < WRN; n++)
                    acc[m][n] = __builtin_amdgcn_mfma_f32_16x16x32_bf16(af[m], bfr[n], acc[m][n], 0, 0, 0);
        }
    };

    const int nt = K / 64;
    loadX(0); loadY(0);
    writeT(0);
    __syncthreads();
    for (int t = 0; t < nt; t++) {
        const int cur = t & 1;
        if (t + 1 < nt) { loadX(t + 1); loadY(t + 1); }  // issue early (hide under MFMA)
        comp(cur);
        if (t + 1 < nt) writeT(cur ^ 1);
        __syncthreads();
    }

    // epilogue: D row = (lane>>4)*4 + i, col = lane&15 (m89-verified C/D map)
    #pragma unroll
    for (int m = 0; m < WRM; m++) {
        const int row0 = m0 + wm0 + m * 16 + ((lane >> 4) << 2);
        #pragma unroll
        for (int n = 0; n < WRN; n++) {
            const int col = n0 + wn0 + n * 16 + (lane & 15);
            f32x4 a = acc[m][n];
            if constexpr (DM == 1) {
                float* Dp = (float*)D + b * db + (long)s * dsn;
                #pragma unroll
                for (int i = 0; i < 4; i++) Dp[(long)(row0 + i) * ldd + col] = a[i];
            } else if constexpr (DM == 0) {
                u16* Dp = (u16*)D + b * db + (long)s * dsn;
                #pragma unroll
                for (int i = 0; i < 4; i++) Dp[(long)(row0 + i) * ldd + col] = f2bf(a[i]);
            } else {
                // locs scatter: row=a, col=s*64+k2 -> VLt[(b*4+s)][a][512+k2] (bf16)
                u16* Dp = (u16*)D;
                const int s2 = col >> 6, k2 = col & 63;
                const long base = (long)(b * 4 + s2) * 4096;
                #pragma unroll
                for (int i = 0; i < 4; i++)
                    Dp[(base + row0 + i) * 576 + 512 + k2] = f2bf(a[i]);
            }
        }
    }
}

// ---------------------------------------------------------------------------
// small kernels
// ---------------------------------------------------------------------------
__global__ void castbf(const float* __restrict__ src, u16* __restrict__ dst, int n8, float scale) {
    int i = blockIdx.x * 256 + threadIdx.x;
    if (i >= n8) return;
    const float* s = src + (long)i * 8;
    u32x4 o;
    #pragma unroll
    for (int j = 0; j < 4; j++) {
        u16 lo = f2bf(s[2 * j] * scale), hi = f2bf(s[2 * j + 1] * scale);
        o[j] = (u32)lo | ((u32)hi << 16);
    }
    *(u32x4*)(dst + (long)i * 8) = o;
}

// cen [b][256][4096] f32 -> cen_t [b][4096][256] bf16
__global__ __launch_bounds__(256) void transpose_cen(const float* __restrict__ cen, u16* __restrict__ cenT) {
    __shared__ float t[64][65];
    const int tx = threadIdx.x & 63, ty = threadIdx.x >> 6;
    const int a0 = blockIdx.x * 64, c0 = blockIdx.y * 64, b = blockIdx.z;
    const float* src = cen + ((long)(b * 256 + c0)) * 4096 + a0;
    #pragma unroll
    for (int i = 0; i < 16; i++) t[ty + i * 4][tx] = src[(long)(ty + i * 4) * 4096 + tx];
    __syncthreads();
    u16* dst = cenT + ((long)b * 4096 + a0) * 256 + c0;
    #pragma unroll
    for (int i = 0; i < 16; i++) dst[(long)(ty + i * 4) * 256 + tx] = f2bf(t[tx][ty + i * 4]);
}

// in-place L2 row-normalize (rowlen 4096 bf16): x *= 1/max(||x||,1e-12)
__global__ __launch_bounds__(256) void rownorm(u16* __restrict__ buf) {
    const long row = blockIdx.x;
    u16* p = buf + row * 4096 + threadIdx.x * 16;
    u32x4 v0 = *(u32x4*)p, v1 = *(u32x4*)(p + 8);
    float ss = 0.f;
    #pragma unroll
    for (int j = 0; j < 4; j++) {
        float a = bf2f(v0[j] & 0xffff), b2 = bf2f(v0[j] >> 16);
        float c = bf2f(v1[j] & 0xffff), d = bf2f(v1[j] >> 16);
        ss += a * a + b2 * b2 + c * c + d * d;
    }
    __shared__ float red[256];
    red[threadIdx.x] = ss; __syncthreads();
    for (int st = 128; st > 0; st >>= 1) {
        if (threadIdx.x < st) red[threadIdx.x] += red[threadIdx.x + st];
        __syncthreads();
    }
    const float inv = 1.f / fmaxf(sqrtf(red[0]), 1e-12f);
    u32x4 o0, o1;
    #pragma unroll
    for (int j = 0; j < 4; j++) {
        o0[j] = (u32)f2bf(bf2f(v0[j] & 0xffff) * inv) | ((u32)f2bf(bf2f(v0[j] >> 16) * inv) << 16);
        o1[j] = (u32)f2bf(bf2f(v1[j] & 0xffff) * inv) | ((u32)f2bf(bf2f(v1[j] >> 16) * inv) << 16);
    }
    *(u32x4*)p = o0; *(u32x4*)(p + 8) = o1;
}

// per (b,s): instance-norm over [64][512] f32 score, row softmax,
// write ws bf16 -> WSWC[...][0:512], wc (sum of 8 chunks) -> [512:576]
__global__ __launch_bounds__(256) void softmax_in(const float* __restrict__ score, u16* __restrict__ wswc) {
    const int bs = blockIdx.x, tid = threadIdx.x;
    const float* S = score + (long)bs * 32768;
    float s1 = 0.f, s2 = 0.f;
    for (int i = tid; i < 32768; i += 256) { float v = S[i]; s1 += v; s2 += v * v; }
    __shared__ float ra[256], rb[256];
    ra[tid] = s1; rb[tid] = s2; __syncthreads();
    for (int st = 128; st > 0; st >>= 1) {
        if (tid < st) { ra[tid] += ra[tid + st]; rb[tid] += rb[tid + st]; }
        __syncthreads();
    }
    const float mu = ra[0] * (1.f / 32768.f);
    const float var = rb[0] * (1.f / 32768.f) - mu * mu;
    const float rstd = rsqrtf(var + 1e-5f);
    const int wid = tid >> 6, lane = tid & 63;
    u16* W = wswc + (long)bs * 64 * 576;
    for (int r = wid; r < 64; r += 4) {
        float zv[8]; float mx = -3.0e38f;
        #pragma unroll
        for (int i = 0; i < 8; i++) { zv[i] = (S[r * 512 + i * 64 + lane] - mu) * rstd; mx = fmaxf(mx, zv[i]); }
        #pragma unroll
        for (int o = 32; o > 0; o >>= 1) mx = fmaxf(mx, __shfl_xor(mx, o));
        float sum = 0.f;
        #pragma unroll
        for (int i = 0; i < 8; i++) { zv[i] = __expf(zv[i] - mx); sum += zv[i]; }
        #pragma unroll
        for (int o = 32; o > 0; o >>= 1) sum += __shfl_xor(sum, o);
        const float inv = 1.f / sum;
        float wcv = 0.f;
        #pragma unroll
        for (int i = 0; i < 8; i++) {  // k = i*64+lane -> j=i, k2=lane
            float w = zv[i] * inv; wcv += w;
            W[r * 576 + i * 64 + lane] = f2bf(w);
        }
        W[r * 576 + 512 + lane] = f2bf(wcv);
    }
}

// BN stats: per channel over (b=4, a=4096): mean + rsqrt(biased var + eps)
__global__ __launch_bounds__(256) void bn_stats(const float* __restrict__ out2, float* __restrict__ st) {
    const int c = blockIdx.x, tid = threadIdx.x;
    float s1 = 0.f, s2 = 0.f;
    for (int i = tid; i < 16384; i += 256) {
        const int b = i >> 12, a = i & 4095;
        float v = out2[((long)(b * 256 + c)) * 4096 + a];
        s1 += v; s2 += v * v;
    }
    __shared__ float ra[256], rb[256];
    ra[tid] = s1; rb[tid] = s2; __syncthreads();
    for (int stp = 128; stp > 0; stp >>= 1) {
        if (tid < stp) { ra[tid] += ra[tid + stp]; rb[tid] += rb[tid + stp]; }
        __syncthreads();
    }
    if (tid == 0) {
        float mu = ra[0] * (1.f / 16384.f);
        float var = rb[0] * (1.f / 16384.f) - mu * mu;
        st[c * 2] = mu;
        st[c * 2 + 1] = rsqrtf(var + 1e-5f);
    }
}

__global__ __launch_bounds__(256) void bn_apply(const float* __restrict__ out2, const float* __restrict__ st,
                                                const float* __restrict__ gamma, const float* __restrict__ beta,
                                                float* __restrict__ out) {
    const long i4 = (long)blockIdx.x * 256 + threadIdx.x;
    const f32x4 v = *(const f32x4*)(out2 + i4 * 4);
    const int c = (int)((i4 * 4) >> 12) & 255;
    const float g = gamma[c] * st[c * 2 + 1];
    const float bt = beta[c] - st[c * 2] * g;
    f32x4 o;
    #pragma unroll
    for (int j = 0; j < 4; j++) o[j] = fmaxf(v[j] * g + bt, 0.f);
    *(f32x4*)(out + i4 * 4) = o;
}

// ---------------------------------------------------------------------------
extern "C" void kernel_launch(void* const* d_in, const int* in_sizes, int n_in,
                              void* d_out, int out_size, void* d_ws, size_t ws_size,
                              hipStream_t stream) {
    (void)in_sizes; (void)n_in; (void)out_size; (void)ws_size;
    const float* cen   = (const float*)d_in[0];
    const float* qw    = (const float*)d_in[1];
    const float* lw    = (const float*)d_in[2];
    const float* kw    = (const float*)d_in[3];
    const float* vw    = (const float*)d_in[4];
    const float* ow    = (const float*)d_in[5];
    const float* gamma = (const float*)d_in[6];
    const float* beta  = (const float*)d_in[7];
    float* out = (float*)d_out;

    char* ws = (char*)d_ws;
    size_t off = 0;
    auto alloc = [&](size_t bytes) { size_t o = off; off += (bytes + 255) & ~(size_t)255; return o; };
    u16*   KWb   = (u16*)(ws + alloc(4L * 512 * 2048 * 2));
    u16*   VWb   = (u16*)(ws + alloc(4L * 512 * 2048 * 2));
    u16*   QWb   = (u16*)(ws + alloc(256L * 256 * 2));
    u16*   LWnb  = (u16*)(ws + alloc(256L * 256 * 2));
    u16*   OWb   = (u16*)(ws + alloc(256L * 256 * 2));
    u16*   cenT  = (u16*)(ws + alloc(4L * 4096 * 256 * 2));
    u16*   keys  = (u16*)(ws + alloc(16L * 512 * 4096 * 2));
    u16*   qs    = (u16*)(ws + alloc(16L * 64 * 4096 * 2));
    u16*   VLt   = (u16*)(ws + alloc(16L * 4096 * 576 * 2));
    float* score = (float*)(ws + alloc(16L * 64 * 512 * 4));
    u16*   WSWC  = (u16*)(ws + alloc(16L * 64 * 576 * 2));
    u16*   out1t = (u16*)(ws + alloc(4L * 4096 * 256 * 2));
    float* out2  = (float*)(ws + alloc(4L * 256 * 4096 * 4));
    float* bnst  = (float*)(ws + alloc(256L * 2 * 4));
    // total ~205 MB

    // weight casts (key/value: [s][512][2048]; q/l/o: [256][256]; local negated)
    castbf<<<dim3(2048), 256, 0, stream>>>(kw, KWb, 524288, 1.f);
    castbf<<<dim3(2048), 256, 0, stream>>>(vw, VWb, 524288, 1.f);
    castbf<<<dim3(32),   256, 0, stream>>>(qw, QWb, 8192, 1.f);
    castbf<<<dim3(32),   256, 0, stream>>>(lw, LWnb, 8192, -1.f);
    castbf<<<dim3(32),   256, 0, stream>>>(ow, OWb, 8192, 1.f);
    transpose_cen<<<dim3(64, 4, 4), 256, 0, stream>>>(cen, cenT);

    // G1 keys[bs][512][4096] = KW[s] · surr_t(b,s)^T   (Y gathered)
    gemm_tn<128,128,4,4, 0,1, 0><<<dim3(4, 32, 16), 256, 0, stream>>>(
        KWb, nullptr, keys, cenT, 2048, 2048, 0, 4096, 2,
        0L, 512L * 2048, 0L, 0L, 4L * 512 * 4096, 512L * 4096);
    // G2 vals_t[bs][4096][512] (into VLt cols 0..511) = surr_t(b,s) · VW[s]^T  (X gathered)
    gemm_tn<128,128,4,4, 1,0, 0><<<dim3(32, 4, 16), 256, 0, stream>>>(
        nullptr, VWb, VLt, cenT, 2048, 0, 2048, 576, 2,
        0L, 0L, 0L, 512L * 2048, 4L * 4096 * 576, 4096L * 576);
    // G3 qs[b][256][4096] = QW_all · cen_t[b]^T
    gemm_tn<128,128,4,4, 0,0, 0><<<dim3(2, 32, 4), 256, 0, stream>>>(
        QWb, cenT, qs, cenT, 256, 256, 256, 4096, 0,
        0L, 0L, 4096L * 256, 0L, 256L * 4096, 0L);
    // G4 -locs_t scattered into VLt[...][512:576] = cen_t[b] · (-LW_all)^T
    gemm_tn<128,128,4,4, 0,0, 2><<<dim3(32, 2, 4), 256, 0, stream>>>(
        cenT, LWnb, VLt, cenT, 256, 256, 256, 0, 0,
        4096L * 256, 0L, 0L, 0L, 0L, 0L);

    rownorm<<<dim3(8192), 256, 0, stream>>>(keys);  // keys -> kn
    rownorm<<<dim3(1024), 256, 0, stream>>>(qs);    // qs -> qn

    // G5 score[bs][64][512] = qn · kn^T  (f32 out)
    gemm_tn<64,64,2,2, 0,0, 1><<<dim3(1, 8, 16), 256, 0, stream>>>(
        qs, keys, score, cenT, 4096, 4096, 4096, 512, 2,
        256L * 4096, 64L * 4096, 4L * 512 * 4096, 512L * 4096, 4L * 64 * 512, 64L * 512);

    softmax_in<<<dim3(16), 256, 0, stream>>>(score, WSWC);

    // G6 out1_t[b][4096][s*64+h] = VLt[bs] · WSWC[bs]^T   (K=576 = 512 ws + 64 wc)
    gemm_tn<128,64,4,2, 0,0, 0><<<dim3(32, 1, 16), 256, 0, stream>>>(
        VLt, WSWC, out1t, cenT, 576, 576, 576, 256, 2,
        4L * 4096 * 576, 4096L * 576, 4L * 64 * 576, 64L * 576, 4096L * 256, 64L);
    // G7 out2[b][256][4096] = OW · out1_t[b]^T  (f32 out)
    gemm_tn<128,128,4,4, 0,0, 1><<<dim3(2, 32, 4), 256, 0, stream>>>(
        OWb, out1t, out2, cenT, 256, 256, 256, 4096, 0,
        0L, 0L, 4096L * 256, 0L, 256L * 4096, 0L);

    bn_stats<<<dim3(256), 256, 0, stream>>>(out2, bnst);
    bn_apply<<<dim3(4096), 256, 0, stream>>>(out2, bnst, gamma, beta, out);
}

// Round 2
// 472.526 us; speedup vs baseline: 1.0555x; 1.0555x over previous
//
#include <hip/hip_runtime.h>

// ExpansionContrastModule on MI355X (gfx950), bf16 MFMA pipeline.
// GEMMs: TN form D[M][N] = X[M][K] · Y[N][K]^T via mfma_f32_16x16x32_bf16.
// Staging: global_load_lds width=16, linear LDS dest + pre-swizzled global
// source (rule #21) + swizzled ds_read. Gather operands redirect OOB lanes'
// global address to a zero page. Row L2-norms accumulated in GEMM epilogues.

typedef unsigned short u16;
typedef unsigned int u32;
typedef __attribute__((ext_vector_type(4))) unsigned int u32x4;
typedef __attribute__((ext_vector_type(8))) short s16x8;
typedef __attribute__((ext_vector_type(4))) float f32x4;

#define DEVFN static __device__ __forceinline__

DEVFN u16 f2bf(float f) {
    u32 u = __builtin_bit_cast(u32, f);
    u32 r = (u + 0x7fffu + ((u >> 16) & 1u)) >> 16;  // RNE
    return (u16)r;
}
DEVFN float bf2f(u32 h) { u32 u = h << 16; return __builtin_bit_cast(float, u); }

typedef __attribute__((address_space(1))) const unsigned int gu32;
typedef __attribute__((address_space(3))) unsigned int lu32;
DEVFN void gld16(const void* g, void* l) {
    __builtin_amdgcn_global_load_lds((gu32*)g, (lu32*)l, 16, 0, 0);
}

// OFFSETS = [(-1,-1),(-1,0),(-1,1),(0,1),(1,1),(1,0),(1,-1),(0,-1)]
__constant__ int cOFFY[8] = {-1,-1,-1, 0, 1, 1, 1, 0};
__constant__ int cOFFX[8] = {-1, 0, 1, 1, 1, 0,-1,-1};

// XOR swizzle within a 128B LDS row (BK=64 bf16): proven conflict-free
// (round-1 profile: SQ_LDS_BANK_CONFLICT = 0).
DEVFN int swz(int r, int kb) { return r * 128 + (kb ^ ((r & 7) << 4)); }

// ---------------------------------------------------------------------------
// TN GEMM. BK=64. 256 threads = 4 waves (2x2). One barrier per K-tile;
// next tile's global_load_lds issued before compute (in flight across comp,
// drained by __syncthreads' vmcnt(0)).
// XG/YG: operand gathered from cen_t with dilated shifts (rows = area idx).
// DM: 0 = bf16 out, 1 = f32 out, 2 = locs scatter into VLt (bf16).
// NRM: atomically accumulate ||row||^2 (of bf16-rounded values) into nrm.
// SCL: scale output by 1/(max(|q|,eps)*max(|k|,eps)) (score GEMM).
// ---------------------------------------------------------------------------
template<int BM, int BN, int WRM, int WRN, int XG, int YG, int DM, int NRM, int SCL>
__global__ __launch_bounds__(256, 2)
void gemm_tn(const u16* __restrict__ X, const u16* __restrict__ Y,
             void* __restrict__ D, const u16* __restrict__ cenT,
             const char* __restrict__ zeroPg, float* __restrict__ nrm,
             const float* __restrict__ nQ, const float* __restrict__ nK,
             int K, int ldx, int ldy, int ldd, int sbits,
             long xb, long xs, long yb, long ys, long db, long dsn,
             long nb, long ns)
{
    const int tid  = threadIdx.x;
    const int lane = tid & 63;
    const int wid  = tid >> 6;
    const int z = blockIdx.z;
    const int b = z >> sbits;
    const int s = z & ((1 << sbits) - 1);
    const int m0 = blockIdx.x * BM;
    const int n0 = blockIdx.y * BN;
    const int dil = s + 1;
    const int wm0 = (wid >> 1) * (WRM * 16);
    const int wn0 = (wid & 1) * (WRN * 16);

    __shared__ __align__(16) char lds[2 * (BM + BN) * 128];

    const char* cenB = (const char*)(cenT + (long)b * (4096 * 256));
    const char* Xb = nullptr;
    const char* Yb = nullptr;
    if constexpr (!XG) Xb = (const char*)(X + b * xb + (long)s * xs + (long)m0 * ldx);
    if constexpr (!YG) Yb = (const char*)(Y + b * yb + (long)s * ys + (long)n0 * ldy);

    // stage one K-tile (X: BM rows, Y: BN rows; 64 k-elems = 128B per row)
    // via global_load_lds: wave-uniform LDS base, per-lane pre-swizzled source.
    auto stage = [&](int bf, int t) {
        char* LX = lds + bf * ((BM + BN) * 128);
        char* LY = LX + BM * 128;
        if constexpr (!XG) {
            const char* base = Xb + (long)t * 128;
            #pragma unroll
            for (int r = 0; r < BM / 32; r++) {
                const int R = r * 32 + wid * 8 + (lane >> 3);
                gld16(base + (long)R * (ldx * 2) + (((lane & 7) * 16) ^ ((R & 7) << 4)),
                      LX + (r * 32 + wid * 8) * 128);
            }
        } else {
            const int j = t >> 2;
            const int dy = cOFFY[j] * dil, dx = cOFFX[j] * dil;
            const int cb = (t & 3) * 128;
            #pragma unroll
            for (int r = 0; r < BM / 32; r++) {
                const int R = r * 32 + wid * 8 + (lane >> 3);
                const int a = m0 + R, yy = (a >> 6) + dy, xx = (a & 63) + dx;
                const int off = ((lane & 7) * 16) ^ ((R & 7) << 4);
                const char* src = (((unsigned)yy < 64u) && ((unsigned)xx < 64u))
                    ? cenB + ((long)((yy << 6) + xx) << 9) + cb + off
                    : zeroPg + off;
                gld16(src, LX + (r * 32 + wid * 8) * 128);
            }
        }
        if constexpr (!YG) {
            const char* base = Yb + (long)t * 128;
            #pragma unroll
            for (int r = 0; r < BN / 32; r++) {
                const int R = r * 32 + wid * 8 + (lane >> 3);
                gld16(base + (long)R * (ldy * 2) + (((lane & 7) * 16) ^ ((R & 7) << 4)),
                      LY + (r * 32 + wid * 8) * 128);
            }
        } else {
            const int j = t >> 2;
            const int dy = cOFFY[j] * dil, dx = cOFFX[j] * dil;
            const int cb = (t & 3) * 128;
            #pragma unroll
            for (int r = 0; r < BN / 32; r++) {
                const int R = r * 32 + wid * 8 + (lane >> 3);
                const int a = n0 + R, yy = (a >> 6) + dy, xx = (a & 63) + dx;
                const int off = ((lane & 7) * 16) ^ ((R & 7) << 4);
                const char* src = (((unsigned)yy < 64u) && ((unsigned)xx < 64u))
                    ? cenB + ((long)((yy << 6) + xx) << 9) + cb + off
                    : zeroPg + off;
                gld16(src, LY + (r * 32 + wid * 8) * 128);
            }
        }
    };

    f32x4 acc[WRM][WRN] = {};

    auto comp = [&](int bf) {
        const char* LX = lds + bf * ((BM + BN) * 128);
        const char* LY = LX + BM * 128;
        #pragma unroll
        for (int kk = 0; kk < 2; kk++) {
            const int kb = kk * 64 + ((lane >> 4) << 4);
            s16x8 af[WRM], bfr[WRN];
            #pragma unroll
            for (int m = 0; m < WRM; m++)
                af[m] = *(const s16x8*)(LX + swz(wm0 + m * 16 + (lane & 15), kb));
            #pragma unroll
            for (int n = 0; n < WRN; n++)
                bfr[n] = *(const s16x8*)(LY + swz(wn0 + n * 16 + (lane & 15), kb));
            #pragma unroll
            for (int m = 0; m < WRM; m++)
                #pragma unroll
                for (int n = 0; n < WRN; n++)
                    acc[m][n] = __builtin_amdgcn_mfma_f32_16x16x32_bf16(af[m], bfr[n], acc[m][n], 0, 0, 0);
        }
    };

    const int nt = K / 64;
    stage(0, 0);
    __syncthreads();           // drains vmcnt(0): tile 0 landed
    int cur = 0;
    for (int t = 0; t < nt; t++) {
        if (t + 1 < nt) stage(cur ^ 1, t + 1);   // in flight across comp
        comp(cur);
        __syncthreads();       // drains vmcnt(0) + orders reads before overwrite
        cur ^= 1;
    }

    // ||row||^2 accumulation (on bf16-rounded values, = what G5 consumes)
    if constexpr (NRM) {
        float* nrmP = nrm + b * nb + s * ns;
        #pragma unroll
        for (int m = 0; m < WRM; m++) {
            float ss[4] = {0.f, 0.f, 0.f, 0.f};
            #pragma unroll
            for (int n = 0; n < WRN; n++)
                #pragma unroll
                for (int i = 0; i < 4; i++) {
                    float v = bf2f(f2bf(acc[m][n][i]));
                    ss[i] += v * v;
                }
            #pragma unroll
            for (int o = 1; o < 16; o <<= 1)
                #pragma unroll
                for (int i = 0; i < 4; i++) ss[i] += __shfl_xor(ss[i], o);
            if ((lane & 15) == 0) {
                const int row0 = m0 + wm0 + m * 16 + ((lane >> 4) << 2);
                #pragma unroll
                for (int i = 0; i < 4; i++) atomicAdd(&nrmP[row0 + i], ss[i]);
            }
        }
    }

    // epilogue: D row = (lane>>4)*4 + i, col = lane&15
    const float* nQp = nullptr; const float* nKp = nullptr;
    if constexpr (SCL) { nQp = nQ + b * 256 + s * 64; nKp = nK + (b * 4 + s) * 512; }
    #pragma unroll
    for (int m = 0; m < WRM; m++) {
        const int row0 = m0 + wm0 + m * 16 + ((lane >> 4) << 2);
        #pragma unroll
        for (int n = 0; n < WRN; n++) {
            const int col = n0 + wn0 + n * 16 + (lane & 15);
            f32x4 a = acc[m][n];
            if constexpr (SCL) {
                const float sk = fmaxf(sqrtf(nKp[col]), 1e-12f);
                #pragma unroll
                for (int i = 0; i < 4; i++) {
                    const float sq = fmaxf(sqrtf(nQp[row0 + i]), 1e-12f);
                    a[i] *= 1.f / (sq * sk);
                }
            }
            if constexpr (DM == 1) {
                float* Dp = (float*)D + b * db + (long)s * dsn;
                #pragma unroll
                for (int i = 0; i < 4; i++) Dp[(long)(row0 + i) * ldd + col] = a[i];
            } else if constexpr (DM == 0) {
                u16* Dp = (u16*)D + b * db + (long)s * dsn;
                #pragma unroll
                for (int i = 0; i < 4; i++) Dp[(long)(row0 + i) * ldd + col] = f2bf(a[i]);
            } else {
                // locs scatter: row=a, col=s2*64+k2 -> VLt[(b*4+s2)][a][512+k2]
                u16* Dp = (u16*)D;
                const int s2 = col >> 6, k2 = col & 63;
                const long base = (long)(b * 4 + s2) * 4096;
                #pragma unroll
                for (int i = 0; i < 4; i++)
                    Dp[(base + row0 + i) * 576 + 512 + k2] = f2bf(a[i]);
            }
        }
    }
}

// ---------------------------------------------------------------------------
// small kernels
// ---------------------------------------------------------------------------
__global__ __launch_bounds__(256) void zero_f32(float* __restrict__ p, int n) {
    int i = blockIdx.x * 256 + threadIdx.x;
    if (i < n) p[i] = 0.f;
}

__global__ void castbf(const float* __restrict__ src, u16* __restrict__ dst, int n8, float scale) {
    int i = blockIdx.x * 256 + threadIdx.x;
    if (i >= n8) return;
    const float* s = src + (long)i * 8;
    u32x4 o;
    #pragma unroll
    for (int j = 0; j < 4; j++) {
        u16 lo = f2bf(s[2 * j] * scale), hi = f2bf(s[2 * j + 1] * scale);
        o[j] = (u32)lo | ((u32)hi << 16);
    }
    *(u32x4*)(dst + (long)i * 8) = o;
}

// cen [b][256][4096] f32 -> cen_t [b][4096][256] bf16
__global__ __launch_bounds__(256) void transpose_cen(const float* __restrict__ cen, u16* __restrict__ cenT) {
    __shared__ float t[64][65];
    const int tx = threadIdx.x & 63, ty = threadIdx.x >> 6;
    const int a0 = blockIdx.x * 64, c0 = blockIdx.y * 64, b = blockIdx.z;
    const float* src = cen + ((long)(b * 256 + c0)) * 4096 + a0;
    #pragma unroll
    for (int i = 0; i < 16; i++) t[ty + i * 4][tx] = src[(long)(ty + i * 4) * 4096 + tx];
    __syncthreads();
    u16* dst = cenT + ((long)b * 4096 + a0) * 256 + c0;
    #pragma unroll
    for (int i = 0; i < 16; i++) dst[(long)(ty + i * 4) * 256 + tx] = f2bf(t[tx][ty + i * 4]);
}

// per (b,s): instance-norm over [64][512] f32 score, row softmax,
// write ws bf16 -> WSWC[...][0:512], wc (sum of 8 chunks) -> [512:576]
__global__ __launch_bounds__(256) void softmax_in(const float* __restrict__ score, u16* __restrict__ wswc) {
    const int bs = blockIdx.x, tid = threadIdx.x;
    const float* S = score + (long)bs * 32768;
    float s1 = 0.f, s2 = 0.f;
    for (int i = tid; i < 32768; i += 256) { float v = S[i]; s1 += v; s2 += v * v; }
    __shared__ float ra[256], rb[256];
    ra[tid] = s1; rb[tid] = s2; __syncthreads();
    for (int st = 128; st > 0; st >>= 1) {
        if (tid < st) { ra[tid] += ra[tid + st]; rb[tid] += rb[tid + st]; }
        __syncthreads();
    }
    const float mu = ra[0] * (1.f / 32768.f);
    const float var = rb[0] * (1.f / 32768.f) - mu * mu;
    const float rstd = rsqrtf(var + 1e-5f);
    const int wid = tid >> 6, lane = tid & 63;
    u16* W = wswc + (long)bs * 64 * 576;
    for (int r = wid; r < 64; r += 4) {
        float zv[8]; float mx = -3.0e38f;
        #pragma unroll
        for (int i = 0; i < 8; i++) { zv[i] = (S[r * 512 + i * 64 + lane] - mu) * rstd; mx = fmaxf(mx, zv[i]); }
        #pragma unroll
        for (int o = 32; o > 0; o >>= 1) mx = fmaxf(mx, __shfl_xor(mx, o));
        float sum = 0.f;
        #pragma unroll
        for (int i = 0; i < 8; i++) { zv[i] = __expf(zv[i] - mx); sum += zv[i]; }
        #pragma unroll
        for (int o = 32; o > 0; o >>= 1) sum += __shfl_xor(sum, o);
        const float inv = 1.f / sum;
        float wcv = 0.f;
        #pragma unroll
        for (int i = 0; i < 8; i++) {
            float w = zv[i] * inv; wcv += w;
            W[r * 576 + i * 64 + lane] = f2bf(w);
        }
        W[r * 576 + 512 + lane] = f2bf(wcv);
    }
}

// BN stats: per channel over (b=4, a=4096): mean + rsqrt(biased var + eps)
__global__ __launch_bounds__(256) void bn_stats(const float* __restrict__ out2, float* __restrict__ st) {
    const int c = blockIdx.x, tid = threadIdx.x;
    float s1 = 0.f, s2 = 0.f;
    for (int i = tid; i < 16384; i += 256) {
        const int b = i >> 12, a = i & 4095;
        float v = out2[((long)(b * 256 + c)) * 4096 + a];
        s1 += v; s2 += v * v;
    }
    __shared__ float ra[256], rb[256];
    ra[tid] = s1; rb[tid] = s2; __syncthreads();
    for (int stp = 128; stp > 0; stp >>= 1) {
        if (tid < stp) { ra[tid] += ra[tid + stp]; rb[tid] += rb[tid + stp]; }
        __syncthreads();
    }
    if (tid == 0) {
        float mu = ra[0] * (1.f / 16384.f);
        float var = rb[0] * (1.f / 16384.f) - mu * mu;
        st[c * 2] = mu;
        st[c * 2 + 1] = rsqrtf(var + 1e-5f);
    }
}

__global__ __launch_bounds__(256) void bn_apply(const float* __restrict__ out2, const float* __restrict__ st,
                                                const float* __restrict__ gamma, const float* __restrict__ beta,
                                                float* __restrict__ out) {
    const long i4 = (long)blockIdx.x * 256 + threadIdx.x;
    const f32x4 v = *(const f32x4*)(out2 + i4 * 4);
    const int c = (int)((i4 * 4) >> 12) & 255;
    const float g = gamma[c] * st[c * 2 + 1];
    const float bt = beta[c] - st[c * 2] * g;
    f32x4 o;
    #pragma unroll
    for (int j = 0; j < 4; j++) o[j] = fmaxf(v[j] * g + bt, 0.f);
    *(f32x4*)(out + i4 * 4) = o;
}

// ---------------------------------------------------------------------------
extern "C" void kernel_launch(void* const* d_in, const int* in_sizes, int n_in,
                              void* d_out, int out_size, void* d_ws, size_t ws_size,
                              hipStream_t stream) {
    (void)in_sizes; (void)n_in; (void)out_size; (void)ws_size;
    const float* cen   = (const float*)d_in[0];
    const float* qw    = (const float*)d_in[1];
    const float* lw    = (const float*)d_in[2];
    const float* kw    = (const float*)d_in[3];
    const float* vw    = (const float*)d_in[4];
    const float* ow    = (const float*)d_in[5];
    const float* gamma = (const float*)d_in[6];
    const float* beta  = (const float*)d_in[7];
    float* out = (float*)d_out;

    char* ws = (char*)d_ws;
    size_t off = 0;
    auto alloc = [&](size_t bytes) { size_t o = off; off += (bytes + 255) & ~(size_t)255; return o; };
    u16*   KWb   = (u16*)(ws + alloc(4L * 512 * 2048 * 2));
    u16*   VWb   = (u16*)(ws + alloc(4L * 512 * 2048 * 2));
    u16*   QWb   = (u16*)(ws + alloc(256L * 256 * 2));
    u16*   LWnb  = (u16*)(ws + alloc(256L * 256 * 2));
    u16*   OWb   = (u16*)(ws + alloc(256L * 256 * 2));
    u16*   cenT  = (u16*)(ws + alloc(4L * 4096 * 256 * 2));
    u16*   keys  = (u16*)(ws + alloc(16L * 512 * 4096 * 2));
    u16*   qs    = (u16*)(ws + alloc(16L * 64 * 4096 * 2));
    u16*   VLt   = (u16*)(ws + alloc(16L * 4096 * 576 * 2));
    float* score = (float*)(ws + alloc(16L * 64 * 512 * 4));
    u16*   WSWC  = (u16*)(ws + alloc(16L * 64 * 576 * 2));
    u16*   out1t = (u16*)(ws + alloc(4L * 4096 * 256 * 2));
    float* out2  = (float*)(ws + alloc(4L * 256 * 4096 * 4));
    float* bnst  = (float*)(ws + alloc(256L * 2 * 4));
    float* nrmB  = (float*)(ws + alloc((64L + 8192 + 1024) * 4));
    char*  zpg = (char*)nrmB;          // 256B zero page
    float* nK  = nrmB + 64;            // [b][s][512] ||key row||^2
    float* nQ  = nrmB + 64 + 8192;     // [b][256]    ||q row||^2

    // prep
    zero_f32<<<dim3(37), 256, 0, stream>>>(nrmB, 9280);
    castbf<<<dim3(2048), 256, 0, stream>>>(kw, KWb, 524288, 1.f);
    castbf<<<dim3(2048), 256, 0, stream>>>(vw, VWb, 524288, 1.f);
    castbf<<<dim3(32),   256, 0, stream>>>(qw, QWb, 8192, 1.f);
    castbf<<<dim3(32),   256, 0, stream>>>(lw, LWnb, 8192, -1.f);
    castbf<<<dim3(32),   256, 0, stream>>>(ow, OWb, 8192, 1.f);
    transpose_cen<<<dim3(64, 4, 4), 256, 0, stream>>>(cen, cenT);

    // G1 keys[bs][512][4096] = KW[s] · surr_t(b,s)^T  (Y gathered) + key norms
    gemm_tn<128,128,4,4, 0,1, 0, 1,0><<<dim3(4, 32, 16), 256, 0, stream>>>(
        KWb, nullptr, keys, cenT, zpg, nK, nullptr, nullptr,
        2048, 2048, 0, 4096, 2,
        0L, 512L * 2048, 0L, 0L, 4L * 512 * 4096, 512L * 4096, 2048L, 512L);
    // G2 vals_t into VLt[...][0:512] = surr_t(b,s) · VW[s]^T  (X gathered)
    gemm_tn<128,128,4,4, 1,0, 0, 0,0><<<dim3(32, 4, 16), 256, 0, stream>>>(
        nullptr, VWb, VLt, cenT, zpg, nullptr, nullptr, nullptr,
        2048, 0, 2048, 576, 2,
        0L, 0L, 0L, 512L * 2048, 4L * 4096 * 576, 4096L * 576, 0L, 0L);
    // G3 qs[b][256][4096] = QW_all · cen_t[b]^T  + q norms
    gemm_tn<128,128,4,4, 0,0, 0, 1,0><<<dim3(2, 32, 4), 256, 0, stream>>>(
        QWb, cenT, qs, cenT, zpg, nQ, nullptr, nullptr,
        256, 256, 256, 4096, 0,
        0L, 0L, 4096L * 256, 0L, 256L * 4096, 0L, 256L, 0L);
    // G4 -locs_t scattered into VLt[...][512:576] = cen_t[b] · (-LW_all)^T
    gemm_tn<128,128,4,4, 0,0, 2, 0,0><<<dim3(32, 2, 4), 256, 0, stream>>>(
        cenT, LWnb, VLt, cenT, zpg, nullptr, nullptr, nullptr,
        256, 256, 256, 0, 0,
        4096L * 256, 0L, 0L, 0L, 0L, 0L, 0L, 0L);

    // G5 score[bs][64][512] = (q·k^T) / (|q||k|)  (f32 out, SCL epilogue)
    gemm_tn<64,64,2,2, 0,0, 1, 0,1><<<dim3(1, 8, 16), 256, 0, stream>>>(
        qs, keys, score, cenT, zpg, nullptr, nQ, nK,
        4096, 4096, 4096, 512, 2,
        256L * 4096, 64L * 4096, 4L * 512 * 4096, 512L * 4096, 4L * 64 * 512, 64L * 512, 0L, 0L);

    softmax_in<<<dim3(16), 256, 0, stream>>>(score, WSWC);

    // G6 out1_t[b][4096][s*64+h] = VLt[bs] · WSWC[bs]^T  (K=576)
    gemm_tn<128,64,4,2, 0,0, 0, 0,0><<<dim3(32, 1, 16), 256, 0, stream>>>(
        VLt, WSWC, out1t, cenT, zpg, nullptr, nullptr, nullptr,
        576, 576, 576, 256, 2,
        4L * 4096 * 576, 4096L * 576, 4L * 64 * 576, 64L * 576, 4096L * 256, 64L, 0L, 0L);
    // G7 out2[b][256][4096] = OW · out1_t[b]^T  (f32 out)
    gemm_tn<128,128,4,4, 0,0, 1, 0,0><<<dim3(2, 32, 4), 256, 0, stream>>>(
        OWb, out1t, out2, cenT, zpg, nullptr, nullptr, nullptr,
        256, 256, 256, 4096, 0,
        0L, 0L, 4096L * 256, 0L, 256L * 4096, 0L, 0L, 0L);

    bn_stats<<<dim3(256), 256, 0, stream>>>(out2, bnst);
    bn_apply<<<dim3(4096), 256, 0, stream>>>(out2, bnst, gamma, beta, out);
}